// Round 2
// baseline (3521.498 us; speedup 1.0000x reference)
//
#include <hip/hip_runtime.h>
#include <hip/hip_bf16.h>

#define BB 256
#define DD 512
#define LL 32
#define HWN 196
#define TT 8

typedef __hip_bfloat16 bf16;

__device__ __forceinline__ float b2f(bf16 x) { return __bfloat162float(x); }
__device__ __forceinline__ bf16 f2b(float x) { return __float2bfloat16(x); }
#define NEG_INF (-__builtin_huge_valf())

// ---------------- small GEMM: out[b,d] = sum_k X[b,k]*W[d,k] + bias[d] ----------------
// X is concat(A1[B,K1], A2[B,K2]); all f32.
__global__ __launch_bounds__(256) void small_gemm_kernel(
    const float* __restrict__ A1, int K1,
    const float* __restrict__ A2, int K2,
    const float* __restrict__ Wt, const float* __restrict__ bias,
    float* __restrict__ outf, int Dout)
{
    __shared__ float xs[1024];
    int b = blockIdx.x, tid = threadIdx.x;
    int K = K1 + K2;
    for (int i = tid; i < K; i += 256) {
        xs[i] = (i < K1) ? A1[(size_t)b*K1 + i] : A2[(size_t)b*K2 + (i - K1)];
    }
    __syncthreads();
    for (int d = tid; d < Dout; d += 256) {
        const float4* wrow = (const float4*)(Wt + (size_t)d * K);
        float acc = 0.f;
        for (int j = 0; j < K/4; ++j) {
            float4 w = wrow[j];
            acc += w.x*xs[j*4] + w.y*xs[j*4+1] + w.z*xs[j*4+2] + w.w*xs[j*4+3];
        }
        if (bias) acc += bias[d];
        outf[(size_t)b*Dout + d] = acc;
    }
}

// ---------------- ControlUnit attention: ca -> mask -> softmax -> c_new ----------------
__global__ __launch_bounds__(256) void control_kernel(
    const float* __restrict__ cq, const float* __restrict__ cw,
    const float* __restrict__ Wca, const float* __restrict__ bca,
    const int* __restrict__ mask,
    float* __restrict__ cnew_f, float* __restrict__ cv_out, float* __restrict__ cnew_out)
{
    __shared__ float u[DD];
    __shared__ float cas[LL];
    __shared__ float cvs[LL];
    int b = blockIdx.x, tid = threadIdx.x;
    for (int d = tid; d < DD; d += 256) u[d] = cq[(size_t)b*DD + d] * Wca[d];
    __syncthreads();
    int wave = tid >> 6, lane = tid & 63;
    float bca0 = bca[0];
    for (int lw = 0; lw < 8; ++lw) {
        int l = wave*8 + lw;
        const float4* w4 = (const float4*)(cw + ((size_t)(b*LL + l))*DD + lane*8);
        float4 wa = w4[0], wb = w4[1];
        const float* uu = &u[lane*8];
        float p = wa.x*uu[0] + wa.y*uu[1] + wa.z*uu[2] + wa.w*uu[3]
                + wb.x*uu[4] + wb.y*uu[5] + wb.z*uu[6] + wb.w*uu[7];
        for (int off = 32; off > 0; off >>= 1) p += __shfl_down(p, off);
        if (lane == 0) {
            float v = p + bca0;
            if (mask[b*LL + l] <= 0) v = NEG_INF;
            cas[l] = v;
        }
    }
    __syncthreads();
    if (tid < LL) {
        float mx = NEG_INF;
        for (int j = 0; j < LL; ++j) mx = fmaxf(mx, cas[j]);
        float s = 0.f;
        for (int j = 0; j < LL; ++j) s += __expf(cas[j] - mx);
        float cv = __expf(cas[tid] - mx) / s;
        cvs[tid] = cv;
        cv_out[b*LL + tid] = cv;
    }
    __syncthreads();
    for (int d = tid; d < DD; d += 256) {
        float acc = 0.f;
        for (int l = 0; l < LL; ++l) acc += cvs[l] * cw[((size_t)(b*LL + l))*DD + d];
        cnew_f[(size_t)b*DD + d] = acc;
        cnew_out[(size_t)b*DD + d] = acc;
    }
}

// ---------------- conv1x1 batched GEMM ----------------
// Y[b,o,hw] = ( sum_c W[o,c]*X[c,hw] + bias[o] ) * (oscale ? oscale[b,o] : 1)
// X = concat_c( X1[b,C1,hw] * (xscale ? xscale[b,c] : 1), X2[b,C2,hw] )
// X1 dtype per X1F32; X2 (if present) always f32; Y dtype per YF32.
template<int X1F32, int YF32>
__global__ __launch_bounds__(256) void conv1x1_kernel(
    const void* __restrict__ X1v, const float* __restrict__ X2,
    const float* __restrict__ xscale,
    const float* __restrict__ Wt, const float* __restrict__ bias,
    const float* __restrict__ oscale,
    void* __restrict__ Yv, int C1, int C2)
{
    __shared__ float Xs[32][208];
    __shared__ float Wsh[64][33];
    int b = blockIdx.y, ot = blockIdx.x;
    int tid = threadIdx.x;
    int to = tid & 15, thw = tid >> 4;
    int C = C1 + C2;
    // zero the pad columns so the unguarded j=12 reads are benign
    for (int idx = tid; idx < 32*12; idx += 256) Xs[idx/12][196 + idx%12] = 0.f;
    float acc[4][13];
    #pragma unroll
    for (int kk = 0; kk < 4; ++kk)
        #pragma unroll
        for (int j = 0; j < 13; ++j) acc[kk][j] = 0.f;

    for (int c0 = 0; c0 < C; c0 += 32) {
        for (int idx = tid; idx < 32*HWN; idx += 256) {
            int cc = idx / HWN, hw = idx % HWN;
            int c = c0 + cc;
            float v;
            if (c < C1) {
                size_t off = ((size_t)b*C1 + c)*HWN + hw;
                v = X1F32 ? ((const float*)X1v)[off] : b2f(((const bf16*)X1v)[off]);
                if (xscale) v *= xscale[(size_t)b*C1 + c];
            } else {
                v = X2[((size_t)b*C2 + (c - C1))*HWN + hw];
            }
            Xs[cc][hw] = v;
        }
        for (int idx = tid; idx < 64*32; idx += 256) {
            int oo = idx >> 5, cc = idx & 31;
            Wsh[oo][cc] = Wt[(size_t)(ot*64 + oo)*C + c0 + cc];
        }
        __syncthreads();
        for (int cc = 0; cc < 32; ++cc) {
            float w0 = Wsh[to][cc], w1 = Wsh[to+16][cc], w2 = Wsh[to+32][cc], w3 = Wsh[to+48][cc];
            #pragma unroll
            for (int j = 0; j < 13; ++j) {
                float x = Xs[cc][thw + 16*j];
                acc[0][j] += w0 * x;
                acc[1][j] += w1 * x;
                acc[2][j] += w2 * x;
                acc[3][j] += w3 * x;
            }
        }
        __syncthreads();
    }
    #pragma unroll
    for (int kk = 0; kk < 4; ++kk) {
        int o = ot*64 + to + 16*kk;
        float bo = bias ? bias[o] : 0.f;
        float sc = oscale ? oscale[(size_t)b*DD + o] : 1.f;
        #pragma unroll
        for (int j = 0; j < 13; ++j) {
            int hw = thw + 16*j;
            if (hw < HWN) {
                float v = (acc[kk][j] + bo) * sc;
                size_t off = ((size_t)b*DD + o)*HWN + hw;
                if (YF32) ((float*)Yv)[off] = v;
                else      ((bf16*)Yv)[off] = f2b(v);
            }
        }
    }
}

// ---------------- channel softmax (over 512 c per (b,hw)) + r[b,c] = sum_hw rv*k --------
__global__ __launch_bounds__(256) void softmax_r_kernel(
    const bf16* __restrict__ ra, const float* __restrict__ kin,
    float* __restrict__ rv, float* __restrict__ r)
{
    __shared__ float mxs[HWN];
    __shared__ float sis[HWN];
    int b = blockIdx.x, tid = threadIdx.x;
    if (tid < HWN) {
        float m = NEG_INF, s = 0.f;
        for (int c = 0; c < DD; ++c) {
            float x = b2f(ra[((size_t)b*DD + c)*HWN + tid]);
            float nm = fmaxf(m, x);
            s = s * __expf(m - nm) + __expf(x - nm);
            m = nm;
        }
        mxs[tid] = m;
        sis[tid] = 1.f / s;
    }
    __syncthreads();
    int wave = tid >> 6, lane = tid & 63;
    for (int ci = 0; ci < 128; ++ci) {
        int c = wave*128 + ci;
        float psum = 0.f;
        #pragma unroll
        for (int g = 0; g < 4; ++g) {
            int hw = lane + 64*g;
            if (hw < HWN) {
                size_t idx = ((size_t)b*DD + c)*HWN + hw;
                float x = b2f(ra[idx]);
                float e = __expf(x - mxs[hw]) * sis[hw];
                rv[idx] = e;
                psum += e * kin[idx];
            }
        }
        for (int off = 32; off > 0; off >>= 1) psum += __shfl_down(psum, off);
        if (lane == 0) r[(size_t)b*DD + c] = psum;
    }
}

// ---------------- gate[b] = sigmoid(dot(c_new[b], Wc) + bc) ----------------
__global__ __launch_bounds__(64) void gate_kernel(
    const float* __restrict__ cnew, const float* __restrict__ Wc, const float* __restrict__ bc,
    float* __restrict__ gate)
{
    int b = blockIdx.x, lane = threadIdx.x;
    const float4* w4 = (const float4*)(Wc + lane*8);
    const float* x = &cnew[(size_t)b*DD + lane*8];
    float4 wa = w4[0], wb = w4[1];
    float p = wa.x*x[0] + wa.y*x[1] + wa.z*x[2] + wa.w*x[3]
            + wb.x*x[4] + wb.y*x[5] + wb.z*x[6] + wb.w*x[7];
    for (int off = 32; off > 0; off >>= 1) p += __shfl_down(p, off);
    if (lane == 0) gate[b] = 1.f / (1.f + __expf(-(p + bc[0])));
}

// ---------------- sa softmax over T and m_sa ----------------
__global__ __launch_bounds__(256) void samsa_kernel(
    const float* __restrict__ cs, const float* __restrict__ ms,
    const float* __restrict__ Wsa, const float* __restrict__ bsa,
    const float* __restrict__ gate, float* __restrict__ msa)
{
    __shared__ float lg[TT];
    __shared__ float sas[TT];
    __shared__ float xw[DD];
    int b = blockIdx.x, tid = threadIdx.x;
    int wave = tid >> 6, lane = tid & 63;
    for (int d = tid; d < DD; d += 256) xw[d] = Wsa[d];
    __syncthreads();
    for (int tw = 0; tw < 2; ++tw) {
        int t = wave + 4*tw;
        const float4* c4 = (const float4*)(cs + ((size_t)t*BB + b)*DD + lane*8);
        float4 ca = c4[0], cb = c4[1];
        const float* ww = &xw[lane*8];
        float p = ca.x*ww[0] + ca.y*ww[1] + ca.z*ww[2] + ca.w*ww[3]
                + cb.x*ww[4] + cb.y*ww[5] + cb.z*ww[6] + cb.w*ww[7];
        for (int off = 32; off > 0; off >>= 1) p += __shfl_down(p, off);
        if (lane == 0) lg[t] = gate[b]*p + bsa[0];
    }
    __syncthreads();
    if (tid < TT) {
        float mx = NEG_INF;
        for (int j = 0; j < TT; ++j) mx = fmaxf(mx, lg[j]);
        float s = 0.f;
        for (int j = 0; j < TT; ++j) s += __expf(lg[j] - mx);
        sas[tid] = __expf(lg[tid] - mx) / s;
    }
    __syncthreads();
    for (int d = tid; d < DD; d += 256) {
        float acc = 0.f;
        for (int t = 0; t < TT; ++t) acc += sas[t] * ms[((size_t)t*BB + b)*DD + d];
        msa[(size_t)b*DD + d] = acc;
    }
}

// ---------------- m_new = g*m + (1-g)*(m_ + msa@Ws^T) ----------------
__global__ __launch_bounds__(256) void final_kernel(
    const float* __restrict__ m, const float* __restrict__ gate,
    const float* __restrict__ mund, const float* __restrict__ msaw,
    float* __restrict__ mnew)
{
    int idx = blockIdx.x*256 + threadIdx.x;
    int b = idx >> 9;
    float g = gate[b];
    mnew[idx] = g * m[idx] + (1.f - g) * (mund[idx] + msaw[idx]);
}

extern "C" void kernel_launch(void* const* d_in, const int* in_sizes, int n_in,
                              void* d_out, int out_size, void* d_ws, size_t ws_size,
                              hipStream_t stream)
{
    (void)in_sizes; (void)n_in; (void)out_size; (void)ws_size;
    const float* c    = (const float*)d_in[0];
    const float* m    = (const float*)d_in[1];
    const float* k    = (const float*)d_in[2];
    const float* q    = (const float*)d_in[3];
    const float* cw   = (const float*)d_in[4];
    const int*   mask = (const int*)  d_in[5];
    const float* cs   = (const float*)d_in[6];
    const float* ms   = (const float*)d_in[7];
    const float* Wcq  = (const float*)d_in[8];
    const float* bcq  = (const float*)d_in[9];
    const float* Wca  = (const float*)d_in[10];
    const float* bca  = (const float*)d_in[11];
    const float* Wm_r = (const float*)d_in[12];
    const float* bm_r = (const float*)d_in[13];
    const float* Wk   = (const float*)d_in[14];
    const float* bk   = (const float*)d_in[15];
    const float* WI   = (const float*)d_in[16];
    const float* bI   = (const float*)d_in[17];
    const float* Wra  = (const float*)d_in[18];
    const float* bra  = (const float*)d_in[19];
    const float* Wm_w = (const float*)d_in[20];
    const float* bm_w = (const float*)d_in[21];
    const float* Wsa  = (const float*)d_in[22];
    const float* bsa  = (const float*)d_in[23];
    const float* Wm2  = (const float*)d_in[24];
    const float* bm2  = (const float*)d_in[25];
    const float* Wc   = (const float*)d_in[26];
    const float* bc   = (const float*)d_in[27];
    const float* Ws   = (const float*)d_in[28];

    float* out_cnew = (float*)d_out;
    float* out_mnew = out_cnew + BB*DD;
    float* out_cv   = out_mnew + BB*DD;
    float* out_rv   = out_cv + BB*LL;     // 25,690,112 f32 — also used to hold I_ (f32) until rv overwrites it

    char* w = (char*)d_ws;
    float* cq_w    = (float*)(w + 0);
    float* cnew_w  = (float*)(w + 524288);
    float* mI_w    = (float*)(w + 1048576);
    float* r_w     = (float*)(w + 1572864);
    float* mprev_w = (float*)(w + 2097152);
    float* mund_w  = (float*)(w + 2621440);
    float* msa_w   = (float*)(w + 3145728);
    float* msaw_w  = (float*)(w + 3670016);
    float* gate_w  = (float*)(w + 4194304);
    bf16*  I_w     = (bf16*)(w + 4195328);           // [B,D,HW] bf16, 51,380,224 bytes
    bf16*  ra_w    = I_w;                            // I dead once I2 computed — reuse
    float* I2_f    = out_rv;                         // I_ lives in the rv slot until softmax

    // ControlUnit
    small_gemm_kernel<<<BB, 256, 0, stream>>>(c, DD, q, DD, Wcq, bcq, cq_w, DD);
    small_gemm_kernel<<<BB, 256, 0, stream>>>(m, DD, nullptr, 0, Wm_r, bm_r, mI_w, DD);
    control_kernel<<<BB, 256, 0, stream>>>(cq_w, cw, Wca, bca, mask, cnew_w, out_cv, out_cnew);
    // ReadUnit: I = mI ⊙ (Wk·k + bk);  I_ = WI·[I;k] + bI;  ra = Wra·(I_ ⊙ c_new) + bra
    conv1x1_kernel<1,0><<<dim3(8, BB), 256, 0, stream>>>(k, nullptr, nullptr, Wk, bk, mI_w, I_w, DD, 0);
    conv1x1_kernel<0,1><<<dim3(8, BB), 256, 0, stream>>>(I_w, k, nullptr, WI, bI, nullptr, I2_f, DD, DD);
    conv1x1_kernel<1,0><<<dim3(8, BB), 256, 0, stream>>>(I2_f, nullptr, cnew_w, Wra, bra, nullptr, ra_w, DD, 0);
    softmax_r_kernel<<<BB, 256, 0, stream>>>(ra_w, k, out_rv, r_w);
    // WriteUnit
    small_gemm_kernel<<<BB, 256, 0, stream>>>(r_w, DD, m, DD, Wm_w, bm_w, mprev_w, DD);
    small_gemm_kernel<<<BB, 256, 0, stream>>>(mprev_w, DD, nullptr, 0, Wm2, bm2, mund_w, DD);
    gate_kernel<<<BB, 64, 0, stream>>>(cnew_w, Wc, bc, gate_w);
    samsa_kernel<<<BB, 256, 0, stream>>>(cs, ms, Wsa, bsa, gate_w, msa_w);
    small_gemm_kernel<<<BB, 256, 0, stream>>>(msa_w, DD, nullptr, 0, Ws, nullptr, msaw_w, DD);
    final_kernel<<<BB*DD/256, 256, 0, stream>>>(m, gate_w, mund_w, msaw_w, out_mnew);
}

// Round 3
// 901.498 us; speedup vs baseline: 3.9063x; 3.9063x over previous
//
#include <hip/hip_runtime.h>
#include <hip/hip_bf16.h>

#define BB 256
#define DD 512
#define LL 32
#define HWN 196
#define TT 8

typedef __hip_bfloat16 bf16;
typedef __attribute__((ext_vector_type(8))) short short8;
typedef __attribute__((ext_vector_type(4))) float f32x4;

__device__ __forceinline__ float b2f(bf16 x) { return __bfloat162float(x); }
__device__ __forceinline__ bf16 f2b(float x) { return __float2bfloat16(x); }
__device__ __forceinline__ unsigned short f2bu(float x) {
    bf16 h = __float2bfloat16(x);
    return *(unsigned short*)&h;
}
#define NEG_INF (-__builtin_huge_valf())

// ---------------- f32 -> bf16 weight convert (vectorized x4) ----------------
__global__ __launch_bounds__(256) void cvt_w_kernel(
    const float* __restrict__ src, unsigned short* __restrict__ dst, int n4)
{
    int i = blockIdx.x*256 + threadIdx.x;
    if (i < n4) {
        float4 f = ((const float4*)src)[i];
        ushort4 u;
        u.x = f2bu(f.x); u.y = f2bu(f.y); u.z = f2bu(f.z); u.w = f2bu(f.w);
        ((ushort4*)dst)[i] = u;
    }
}

// ---------------- small GEMM: out[b,d] = sum_k X[b,k]*W[d,k] + bias[d] ----------------
__global__ __launch_bounds__(256) void small_gemm_kernel(
    const float* __restrict__ A1, int K1,
    const float* __restrict__ A2, int K2,
    const float* __restrict__ Wt, const float* __restrict__ bias,
    float* __restrict__ outf, int Dout)
{
    __shared__ float xs[1024];
    int b = blockIdx.x, tid = threadIdx.x;
    int K = K1 + K2;
    for (int i = tid; i < K; i += 256) {
        xs[i] = (i < K1) ? A1[(size_t)b*K1 + i] : A2[(size_t)b*K2 + (i - K1)];
    }
    __syncthreads();
    for (int d = tid; d < Dout; d += 256) {
        const float4* wrow = (const float4*)(Wt + (size_t)d * K);
        float acc = 0.f;
        for (int j = 0; j < K/4; ++j) {
            float4 w = wrow[j];
            acc += w.x*xs[j*4] + w.y*xs[j*4+1] + w.z*xs[j*4+2] + w.w*xs[j*4+3];
        }
        if (bias) acc += bias[d];
        outf[(size_t)b*Dout + d] = acc;
    }
}

// ---------------- ControlUnit attention ----------------
__global__ __launch_bounds__(256) void control_kernel(
    const float* __restrict__ cq, const float* __restrict__ cw,
    const float* __restrict__ Wca, const float* __restrict__ bca,
    const int* __restrict__ mask,
    float* __restrict__ cnew_f, float* __restrict__ cv_out, float* __restrict__ cnew_out)
{
    __shared__ float u[DD];
    __shared__ float cas[LL];
    __shared__ float cvs[LL];
    int b = blockIdx.x, tid = threadIdx.x;
    for (int d = tid; d < DD; d += 256) u[d] = cq[(size_t)b*DD + d] * Wca[d];
    __syncthreads();
    int wave = tid >> 6, lane = tid & 63;
    float bca0 = bca[0];
    for (int lw = 0; lw < 8; ++lw) {
        int l = wave*8 + lw;
        const float4* w4 = (const float4*)(cw + ((size_t)(b*LL + l))*DD + lane*8);
        float4 wa = w4[0], wb = w4[1];
        const float* uu = &u[lane*8];
        float p = wa.x*uu[0] + wa.y*uu[1] + wa.z*uu[2] + wa.w*uu[3]
                + wb.x*uu[4] + wb.y*uu[5] + wb.z*uu[6] + wb.w*uu[7];
        for (int off = 32; off > 0; off >>= 1) p += __shfl_down(p, off);
        if (lane == 0) {
            float v = p + bca0;
            if (mask[b*LL + l] <= 0) v = NEG_INF;
            cas[l] = v;
        }
    }
    __syncthreads();
    if (tid < LL) {
        float mx = NEG_INF;
        for (int j = 0; j < LL; ++j) mx = fmaxf(mx, cas[j]);
        float s = 0.f;
        for (int j = 0; j < LL; ++j) s += __expf(cas[j] - mx);
        float cv = __expf(cas[tid] - mx) / s;
        cvs[tid] = cv;
        cv_out[b*LL + tid] = cv;
    }
    __syncthreads();
    for (int d = tid; d < DD; d += 256) {
        float acc = 0.f;
        for (int l = 0; l < LL; ++l) acc += cvs[l] * cw[((size_t)(b*LL + l))*DD + d];
        cnew_f[(size_t)b*DD + d] = acc;
        cnew_out[(size_t)b*DD + d] = acc;
    }
}

// ---------------- load 4 consecutive channel-rows x 4 hw cols, as bf16 bits ----------------
__device__ __forceinline__ void load4rows(const void* X, int isf32, size_t row, int n4, ushort4 r[4]) {
    if (isf32) {
        const float* p = (const float*)X + row*HWN + n4*4;
        #pragma unroll
        for (int i = 0; i < 4; ++i) {
            float4 f = *(const float4*)(p + (size_t)i*HWN);
            r[i].x = f2bu(f.x); r[i].y = f2bu(f.y); r[i].z = f2bu(f.z); r[i].w = f2bu(f.w);
        }
    } else {
        const unsigned short* p = (const unsigned short*)X + row*HWN + n4*4;
        #pragma unroll
        for (int i = 0; i < 4; ++i) r[i] = *(const ushort4*)(p + (size_t)i*HWN);
    }
}

// ---------------- MFMA conv1x1 batched GEMM ----------------
// Y[b,o,hw] = (sum_c W[o,c]*X[c,hw] + bias[o]) * (oscale ? oscale[b,o] : 1)
// X = concat_c(X1[b,C1,hw], X2[b,C-C1,hw]); each source f32 or bf16.
// Block: 256 thr = 4 waves; wave (wm,wn): 4 m-tiles x 7 n-tiles of 16x16x32 MFMA.
// Grid: (4 ot, 256 b). Weights Wb pre-converted bf16, A-frags read from global (L2).
__global__ __launch_bounds__(256) void conv_mfma_kernel(
    const void* __restrict__ X1, int x1f32, int C1,
    const void* __restrict__ X2, int x2f32,
    const unsigned short* __restrict__ Wb, int C,
    const float* __restrict__ bias, const float* __restrict__ oscale,
    unsigned short* __restrict__ Y)
{
    // Xs[kq][n]: kq = (k within 32-step)/4, cell = 4 bf16 along k. stride 212 (2*212 mod 32 = 8 -> 2-way banks)
    __shared__ __align__(16) uint2 Xs[8*212];
    int b = blockIdx.y, ot = blockIdx.x;
    int tid = threadIdx.x;
    int wave = tid >> 6, lane = tid & 63;
    int wm = wave >> 1, wn = wave & 1;
    int obase = ot*128 + wm*64;
    int n0 = wn*96;               // wn0: n 0..111, wn1: n 96..207 (overlap tile = duplicate store, benign)
    int ln = lane & 15, lq = lane >> 4;
    int C2 = C - C1;

    f32x4 acc[4][7];
    #pragma unroll
    for (int mt = 0; mt < 4; ++mt)
        #pragma unroll
        for (int nt = 0; nt < 7; ++nt) acc[mt][nt] = (f32x4){0.f, 0.f, 0.f, 0.f};

    for (int c0 = 0; c0 < C; c0 += 32) {
        __syncthreads();
        // ---- stage + transpose X tile: [32 k x 196 n] -> Xs[kq][n] (k-quads packed) ----
        for (int idx = tid; idx < 8*49; idx += 256) {
            int n4 = idx % 49, kq = idx / 49;
            int c = c0 + kq*4;
            ushort4 r[4];
            if (c < C1) load4rows(X1, x1f32, (size_t)b*C1 + c, n4, r);
            else        load4rows(X2, x2f32, (size_t)b*C2 + (c - C1), n4, r);
            uint2* cell = &Xs[kq*212 + n4*4];
            *(uint4*)(cell) = make_uint4(
                (uint)r[0].x | ((uint)r[1].x << 16), (uint)r[2].x | ((uint)r[3].x << 16),
                (uint)r[0].y | ((uint)r[1].y << 16), (uint)r[2].y | ((uint)r[3].y << 16));
            *(uint4*)(cell + 2) = make_uint4(
                (uint)r[0].z | ((uint)r[1].z << 16), (uint)r[2].z | ((uint)r[3].z << 16),
                (uint)r[0].w | ((uint)r[1].w << 16), (uint)r[2].w | ((uint)r[3].w << 16));
        }
        __syncthreads();
        // ---- A-fragments straight from global (bf16 weights, L2-resident) ----
        short8 a[4];
        #pragma unroll
        for (int mt = 0; mt < 4; ++mt)
            a[mt] = *(const short8*)(Wb + (size_t)(obase + mt*16 + ln)*C + c0 + lq*8);
        // ---- MFMA over 7 n-tiles ----
        #pragma unroll
        for (int nt = 0; nt < 7; ++nt) {
            int n = n0 + nt*16 + ln;
            uint2 b0 = Xs[(lq*2)*212 + n];
            uint2 b1 = Xs[(lq*2 + 1)*212 + n];
            union { uint4 u; short8 s; } bb;
            bb.u = make_uint4(b0.x, b0.y, b1.x, b1.y);
            #pragma unroll
            for (int mt = 0; mt < 4; ++mt)
                acc[mt][nt] = __builtin_amdgcn_mfma_f32_16x16x32_bf16(a[mt], bb.s, acc[mt][nt], 0, 0, 0);
        }
    }
    // ---- epilogue: C/D layout col = lane&15, row = (lane>>4)*4 + reg ----
    #pragma unroll
    for (int mt = 0; mt < 4; ++mt) {
        #pragma unroll
        for (int rr = 0; rr < 4; ++rr) {
            int o = obase + mt*16 + lq*4 + rr;
            float bo = bias[o];
            float os = oscale ? oscale[(size_t)b*DD + o] : 1.f;
            #pragma unroll
            for (int nt = 0; nt < 7; ++nt) {
                int hw = n0 + nt*16 + ln;
                if (hw < HWN) {
                    float v = (acc[mt][nt][rr] + bo) * os;
                    Y[((size_t)b*DD + o)*HWN + hw] = f2bu(v);
                }
            }
        }
    }
}

// ---------------- channel softmax (512 c per (b,hw)) + r[b,c] = sum_hw rv*k ----------------
__global__ __launch_bounds__(512) void softmax_r_kernel(
    const bf16* __restrict__ ra, const float* __restrict__ kin,
    float* __restrict__ rv, float* __restrict__ r)
{
    __shared__ float pm[2][HWN], ps[2][HWN];
    __shared__ float mxs[HWN], sis[HWN];
    int b = blockIdx.x, tid = threadIdx.x;
    int half = tid >> 8, hw = tid & 255;
    if (hw < HWN) {
        float m = NEG_INF, s = 0.f;
        const bf16* base = ra + ((size_t)b*DD + half*256)*HWN + hw;
        for (int c = 0; c < 256; ++c) {
            float x = b2f(base[(size_t)c*HWN]);
            float nm = fmaxf(m, x);
            s = s*__expf(m - nm) + __expf(x - nm);
            m = nm;
        }
        pm[half][hw] = m; ps[half][hw] = s;
    }
    __syncthreads();
    if (tid < HWN) {
        float m0 = pm[0][tid], m1 = pm[1][tid];
        float m = fmaxf(m0, m1);
        float s = ps[0][tid]*__expf(m0 - m) + ps[1][tid]*__expf(m1 - m);
        mxs[tid] = m; sis[tid] = 1.f/s;
    }
    __syncthreads();
    int wave = tid >> 6, lane = tid & 63;
    for (int ci = 0; ci < 64; ++ci) {
        int c = wave*64 + ci;
        float psum = 0.f;
        #pragma unroll
        for (int g = 0; g < 4; ++g) {
            int hw2 = lane + 64*g;
            if (hw2 < HWN) {
                size_t idx = ((size_t)b*DD + c)*HWN + hw2;
                float e = __expf(b2f(ra[idx]) - mxs[hw2]) * sis[hw2];
                rv[idx] = e;
                psum += e * kin[idx];
            }
        }
        for (int off = 32; off > 0; off >>= 1) psum += __shfl_down(psum, off);
        if (lane == 0) r[(size_t)b*DD + c] = psum;
    }
}

// ---------------- gate[b] = sigmoid(dot(c_new[b], Wc) + bc) ----------------
__global__ __launch_bounds__(64) void gate_kernel(
    const float* __restrict__ cnew, const float* __restrict__ Wc, const float* __restrict__ bc,
    float* __restrict__ gate)
{
    int b = blockIdx.x, lane = threadIdx.x;
    const float4* w4 = (const float4*)(Wc + lane*8);
    const float* x = &cnew[(size_t)b*DD + lane*8];
    float4 wa = w4[0], wb = w4[1];
    float p = wa.x*x[0] + wa.y*x[1] + wa.z*x[2] + wa.w*x[3]
            + wb.x*x[4] + wb.y*x[5] + wb.z*x[6] + wb.w*x[7];
    for (int off = 32; off > 0; off >>= 1) p += __shfl_down(p, off);
    if (lane == 0) gate[b] = 1.f / (1.f + __expf(-(p + bc[0])));
}

// ---------------- sa softmax over T and m_sa ----------------
__global__ __launch_bounds__(256) void samsa_kernel(
    const float* __restrict__ cs, const float* __restrict__ ms,
    const float* __restrict__ Wsa, const float* __restrict__ bsa,
    const float* __restrict__ gate, float* __restrict__ msa)
{
    __shared__ float lg[TT];
    __shared__ float sas[TT];
    __shared__ float xw[DD];
    int b = blockIdx.x, tid = threadIdx.x;
    int wave = tid >> 6, lane = tid & 63;
    for (int d = tid; d < DD; d += 256) xw[d] = Wsa[d];
    __syncthreads();
    for (int tw = 0; tw < 2; ++tw) {
        int t = wave + 4*tw;
        const float4* c4 = (const float4*)(cs + ((size_t)t*BB + b)*DD + lane*8);
        float4 ca = c4[0], cb = c4[1];
        const float* ww = &xw[lane*8];
        float p = ca.x*ww[0] + ca.y*ww[1] + ca.z*ww[2] + ca.w*ww[3]
                + cb.x*ww[4] + cb.y*ww[5] + cb.z*ww[6] + cb.w*ww[7];
        for (int off = 32; off > 0; off >>= 1) p += __shfl_down(p, off);
        if (lane == 0) lg[t] = gate[b]*p + bsa[0];
    }
    __syncthreads();
    if (tid < TT) {
        float mx = NEG_INF;
        for (int j = 0; j < TT; ++j) mx = fmaxf(mx, lg[j]);
        float s = 0.f;
        for (int j = 0; j < TT; ++j) s += __expf(lg[j] - mx);
        sas[tid] = __expf(lg[tid] - mx) / s;
    }
    __syncthreads();
    for (int d = tid; d < DD; d += 256) {
        float acc = 0.f;
        for (int t = 0; t < TT; ++t) acc += sas[t] * ms[((size_t)t*BB + b)*DD + d];
        msa[(size_t)b*DD + d] = acc;
    }
}

// ---------------- m_new = g*m + (1-g)*(m_ + msa@Ws^T) ----------------
__global__ __launch_bounds__(256) void final_kernel(
    const float* __restrict__ m, const float* __restrict__ gate,
    const float* __restrict__ mund, const float* __restrict__ msaw,
    float* __restrict__ mnew)
{
    int idx = blockIdx.x*256 + threadIdx.x;
    int b = idx >> 9;
    float g = gate[b];
    float mm = m[idx], mu = mund[idx], mw = msaw[idx];
    mnew[idx] = g * mm + (1.f - g) * (mu + mw);
}

extern "C" void kernel_launch(void* const* d_in, const int* in_sizes, int n_in,
                              void* d_out, int out_size, void* d_ws, size_t ws_size,
                              hipStream_t stream)
{
    (void)in_sizes; (void)n_in; (void)out_size; (void)ws_size;
    const float* c    = (const float*)d_in[0];
    const float* m    = (const float*)d_in[1];
    const float* k    = (const float*)d_in[2];
    const float* q    = (const float*)d_in[3];
    const float* cw   = (const float*)d_in[4];
    const int*   mask = (const int*)  d_in[5];
    const float* cs   = (const float*)d_in[6];
    const float* ms   = (const float*)d_in[7];
    const float* Wcq  = (const float*)d_in[8];
    const float* bcq  = (const float*)d_in[9];
    const float* Wca  = (const float*)d_in[10];
    const float* bca  = (const float*)d_in[11];
    const float* Wm_r = (const float*)d_in[12];
    const float* bm_r = (const float*)d_in[13];
    const float* Wk   = (const float*)d_in[14];
    const float* bk   = (const float*)d_in[15];
    const float* WI   = (const float*)d_in[16];
    const float* bI   = (const float*)d_in[17];
    const float* Wra  = (const float*)d_in[18];
    const float* bra  = (const float*)d_in[19];
    const float* Wm_w = (const float*)d_in[20];
    const float* bm_w = (const float*)d_in[21];
    const float* Wsa  = (const float*)d_in[22];
    const float* bsa  = (const float*)d_in[23];
    const float* Wm2  = (const float*)d_in[24];
    const float* bm2  = (const float*)d_in[25];
    const float* Wc   = (const float*)d_in[26];
    const float* bc   = (const float*)d_in[27];
    const float* Ws   = (const float*)d_in[28];

    float* out_cnew = (float*)d_out;
    float* out_mnew = out_cnew + BB*DD;
    float* out_cv   = out_mnew + BB*DD;
    float* out_rv   = out_cv + BB*LL;     // 25,690,112 f32 = 102,760,448 B

    // d_out rv region doubles as bf16 scratch for I / I2' (both dead before rv is written)
    unsigned short* I_w  = (unsigned short*)out_rv;                       // 51,380,224 B
    unsigned short* I2_w = (unsigned short*)((char*)out_rv + 51380224);   // 51,380,224 B

    char* w = (char*)d_ws;                 // total footprint: 55,575,552 B
    float* s0      = (float*)(w + 0);        // cq -> r
    float* s1      = (float*)(w + 524288);   // cnew
    float* s2      = (float*)(w + 1048576);  // mI -> mund
    float* s3      = (float*)(w + 1572864);  // mprev -> msa
    unsigned short* Wkb  = (unsigned short*)(w + 2097152);   // 512x512 bf16
    unsigned short* WIb  = (unsigned short*)(w + 2621440);   // 512x1024 bf16
    unsigned short* Wrab = (unsigned short*)(w + 3670016);   // 512x512 bf16
    unsigned short* ra_w = (unsigned short*)(w + 4194304);   // [B,D,HW] bf16, 51,380,224 B
    float* gate_w  = (float*)(w + 55574528); // 1024 B

    float* cq_w   = s0;
    float* r_w    = s0;
    float* cnew_w = s1;
    float* mI_w   = s2;
    float* mund_w = s2;
    float* mprev_w= s3;
    float* msa_w  = s3;
    float* msaw_w = out_mnew;   // f32 scratch; final_kernel reads then overwrites same idx

    // Weight converts (f32 -> bf16), L2-resident thereafter
    cvt_w_kernel<<<256, 256, 0, stream>>>(Wk,  Wkb,  65536);
    cvt_w_kernel<<<512, 256, 0, stream>>>(WI,  WIb,  131072);
    cvt_w_kernel<<<256, 256, 0, stream>>>(Wra, Wrab, 65536);

    // ControlUnit
    small_gemm_kernel<<<BB, 256, 0, stream>>>(c, DD, q, DD, Wcq, bcq, cq_w, DD);
    small_gemm_kernel<<<BB, 256, 0, stream>>>(m, DD, nullptr, 0, Wm_r, bm_r, mI_w, DD);
    control_kernel<<<BB, 256, 0, stream>>>(cq_w, cw, Wca, bca, mask, cnew_w, out_cv, out_cnew);

    // ReadUnit (MFMA convs): I = mI.(Wk k + bk); I2' = (WI [I;k] + bI).cnew; ra = Wra I2' + bra
    conv_mfma_kernel<<<dim3(4, BB), 256, 0, stream>>>(k,    1, DD, nullptr, 0, Wkb,  DD,   bk,  mI_w,   I_w);
    conv_mfma_kernel<<<dim3(4, BB), 256, 0, stream>>>(I_w,  0, DD, k,       1, WIb,  2*DD, bI,  cnew_w, I2_w);
    conv_mfma_kernel<<<dim3(4, BB), 256, 0, stream>>>(I2_w, 0, DD, nullptr, 0, Wrab, DD,   bra, nullptr, ra_w);
    softmax_r_kernel<<<BB, 512, 0, stream>>>((const bf16*)ra_w, k, out_rv, r_w);

    // WriteUnit
    small_gemm_kernel<<<BB, 256, 0, stream>>>(r_w, DD, m, DD, Wm_w, bm_w, mprev_w, DD);
    small_gemm_kernel<<<BB, 256, 0, stream>>>(mprev_w, DD, nullptr, 0, Wm2, bm2, mund_w, DD);
    gate_kernel<<<BB, 64, 0, stream>>>(cnew_w, Wc, bc, gate_w);
    samsa_kernel<<<BB, 256, 0, stream>>>(cs, ms, Wsa, bsa, gate_w, msa_w);
    small_gemm_kernel<<<BB, 256, 0, stream>>>(msa_w, DD, nullptr, 0, Ws, nullptr, msaw_w, DD);
    final_kernel<<<BB*DD/256, 256, 0, stream>>>(m, gate_w, mund_w, msaw_w, out_mnew);
}